// Round 1
// baseline (214.641 us; speedup 1.0000x reference)
//
#include <hip/hip_runtime.h>
#include <math.h>

#define BS 32
#define OBJ 128
#define DD 256
#define RR 32
#define EE 64
#define NDEPTH 3

// ---------------------------------------------------------------------------
// Reduce A [32,128,4096] -> Ao [32,128,128] (sum over r within each o2-group
// of 32), Ar [32,128,32] (sum over o2 at fixed r), As [32,128] (total).
// One wave per (b,o) row; fully coalesced float4 loads.
// ---------------------------------------------------------------------------
__global__ __launch_bounds__(256) void k_reduceA(const float* __restrict__ A,
                                                 float* __restrict__ Ao,
                                                 float* __restrict__ Ar,
                                                 float* __restrict__ As) {
    int wave = threadIdx.x >> 6;
    int lane = threadIdx.x & 63;
    int row  = blockIdx.x * 4 + wave;              // 0..4095 == b*OBJ+o
    const float4* src = (const float4*)(A + (size_t)row * (RR * OBJ));
    float* AoRow = Ao + (size_t)row * OBJ;

    float4 arAcc = make_float4(0.f, 0.f, 0.f, 0.f);
#pragma unroll
    for (int it = 0; it < 16; ++it) {
        float4 v = src[it * 64 + lane];            // elem n = it*256 + lane*4 + j
        arAcc.x += v.x; arAcc.y += v.y; arAcc.z += v.z; arAcc.w += v.w;
        // Ao group g = it*8 + (lane>>3); lanes 8k..8k+7 share a group
        float s = v.x + v.y + v.z + v.w;
        s += __shfl_xor(s, 1);
        s += __shfl_xor(s, 2);
        s += __shfl_xor(s, 4);
        if ((lane & 7) == 0) AoRow[it * 8 + (lane >> 3)] = s;
    }
    // Ar: r = 4*(lane&7)+j, reduce over lanes differing in bits 3..5
#pragma unroll
    for (int m = 8; m <= 32; m <<= 1) {
        arAcc.x += __shfl_xor(arAcc.x, m);
        arAcc.y += __shfl_xor(arAcc.y, m);
        arAcc.z += __shfl_xor(arAcc.z, m);
        arAcc.w += __shfl_xor(arAcc.w, m);
    }
    if (lane < 8) ((float4*)(Ar + (size_t)row * RR))[lane] = arAcc;
    // As: total row sum
    float t = arAcc.x + arAcc.y + arAcc.z + arAcc.w;
    t += __shfl_xor(t, 1);
    t += __shfl_xor(t, 2);
    t += __shfl_xor(t, 4);
    if (lane == 0) As[row] = t;
}

// ---------------------------------------------------------------------------
// relpart[d][r][f] = sum_e rel_table[r,e] * W2[d][DD+e][f]   (3*32*256)
// ---------------------------------------------------------------------------
__global__ __launch_bounds__(256) void k_rel(const float* __restrict__ rel,
                                             const float* __restrict__ W2,
                                             float* __restrict__ relpart) {
    int dr = blockIdx.x;            // d*32 + r
    int d = dr >> 5, r = dr & 31;
    int f = threadIdx.x;
    const float* w  = W2 + (size_t)d * (DD + EE) * DD + (size_t)DD * DD;
    const float* rl = rel + (size_t)r * EE;
    float acc = 0.f;
#pragma unroll 8
    for (int e = 0; e < EE; ++e)
        acc = fmaf(rl[e], w[(size_t)e * DD + f], acc);
    relpart[(size_t)dr * DD + f] = acc;
}

// ---------------------------------------------------------------------------
// K1: C[4096 x 512] = X[4096 x 256] @ [W1[d] | W2a[d]] (each 256x256, row-major
// [in,out]).  Cols 0..255 -> h1 (+b1[d]); cols 256..511 -> xw.
// 64x64 tile / 256 threads / 4x4 microtile / BK=32.
// ---------------------------------------------------------------------------
__global__ __launch_bounds__(256) void k_gemm1(const float* __restrict__ X,
                                               const float* __restrict__ W1,
                                               const float* __restrict__ W2,
                                               const float* __restrict__ b1,
                                               int d,
                                               float* __restrict__ h1,
                                               float* __restrict__ xw) {
    __shared__ float Xs[64][33];
    __shared__ float Ws[32][64];

    int m0 = blockIdx.y * 64;
    int n0blk = blockIdx.x * 64;                   // 0..448
    bool isW1 = (n0blk < 256);
    int ncol0 = isW1 ? n0blk : (n0blk - 256);
    const float* Wbase = isW1 ? (W1 + (size_t)d * DD * DD)
                              : (W2 + (size_t)d * (DD + EE) * DD);

    int tid = threadIdx.x;
    int tx = tid & 15;            // n quad
    int ty = tid >> 4;            // m quad
    float acc[4][4] = {};

    for (int k0 = 0; k0 < 256; k0 += 32) {
#pragma unroll
        for (int i = 0; i < 2; ++i) {              // X tile 64x32
            int idx = tid + 256 * i;
            int rrow = idx >> 3, c4 = idx & 7;
            float4 v = *(const float4*)(X + (size_t)(m0 + rrow) * DD + k0 + c4 * 4);
            Xs[rrow][c4 * 4 + 0] = v.x; Xs[rrow][c4 * 4 + 1] = v.y;
            Xs[rrow][c4 * 4 + 2] = v.z; Xs[rrow][c4 * 4 + 3] = v.w;
        }
#pragma unroll
        for (int i = 0; i < 2; ++i) {              // W tile 32x64
            int idx = tid + 256 * i;
            int rrow = idx >> 4, c4 = idx & 15;
            *(float4*)(&Ws[rrow][c4 * 4]) =
                *(const float4*)(Wbase + (size_t)(k0 + rrow) * DD + ncol0 + c4 * 4);
        }
        __syncthreads();
#pragma unroll
        for (int kk = 0; kk < 32; ++kk) {
            float a0 = Xs[ty * 4 + 0][kk];
            float a1 = Xs[ty * 4 + 1][kk];
            float a2 = Xs[ty * 4 + 2][kk];
            float a3 = Xs[ty * 4 + 3][kk];
            float4 bv = *(const float4*)(&Ws[kk][tx * 4]);
            acc[0][0] = fmaf(a0, bv.x, acc[0][0]);
            acc[0][1] = fmaf(a0, bv.y, acc[0][1]);
            acc[0][2] = fmaf(a0, bv.z, acc[0][2]);
            acc[0][3] = fmaf(a0, bv.w, acc[0][3]);
            acc[1][0] = fmaf(a1, bv.x, acc[1][0]);
            acc[1][1] = fmaf(a1, bv.y, acc[1][1]);
            acc[1][2] = fmaf(a1, bv.z, acc[1][2]);
            acc[1][3] = fmaf(a1, bv.w, acc[1][3]);
            acc[2][0] = fmaf(a2, bv.x, acc[2][0]);
            acc[2][1] = fmaf(a2, bv.y, acc[2][1]);
            acc[2][2] = fmaf(a2, bv.z, acc[2][2]);
            acc[2][3] = fmaf(a2, bv.w, acc[2][3]);
            acc[3][0] = fmaf(a3, bv.x, acc[3][0]);
            acc[3][1] = fmaf(a3, bv.y, acc[3][1]);
            acc[3][2] = fmaf(a3, bv.z, acc[3][2]);
            acc[3][3] = fmaf(a3, bv.w, acc[3][3]);
        }
        __syncthreads();
    }

    float4 bias = make_float4(0.f, 0.f, 0.f, 0.f);
    if (isW1) bias = *(const float4*)(b1 + (size_t)d * DD + ncol0 + tx * 4);
    float* dst = isW1 ? h1 : xw;
#pragma unroll
    for (int i = 0; i < 4; ++i) {
        float4 o;
        o.x = acc[i][0] + bias.x;
        o.y = acc[i][1] + bias.y;
        o.z = acc[i][2] + bias.z;
        o.w = acc[i][3] + bias.w;
        *(float4*)(dst + (size_t)(m0 + ty * 4 + i) * DD + ncol0 + tx * 4) = o;
    }
}

// ---------------------------------------------------------------------------
// K2 (per batch): agg = Ao[b](128x128) @ xw[b](128x256)
//                     + Ar[b](128x32) @ relpart[d](32x256)
// out = tanh(agg + As[b,o]*b2[d] + h1 + x)
// grid: (nTile=4, mTile=2, b=32); 64x64 tile, 4x4 microtile, BK=32 (5 K-tiles).
// ---------------------------------------------------------------------------
__global__ __launch_bounds__(256) void k_agg(const float* __restrict__ Ao,
                                             const float* __restrict__ Ar,
                                             const float* __restrict__ As,
                                             const float* __restrict__ relpart,
                                             const float* __restrict__ b2,
                                             int d,
                                             const float* __restrict__ xw,
                                             const float* __restrict__ h1,
                                             const float* __restrict__ xin,
                                             float* __restrict__ xout) {
    __shared__ float Asm[64][33];
    __shared__ float Bs[32][64];

    int b  = blockIdx.z;
    int m0 = blockIdx.y * 64;
    int n0 = blockIdx.x * 64;
    int tid = threadIdx.x;
    int tx = tid & 15, ty = tid >> 4;

    const float* AoB = Ao + ((size_t)b * OBJ + m0) * OBJ;
    const float* ArB = Ar + ((size_t)b * OBJ + m0) * RR;
    const float* xwB = xw + (size_t)b * OBJ * DD;
    const float* rp  = relpart + (size_t)d * RR * DD;

    float acc[4][4] = {};

    for (int t = 0; t < 5; ++t) {
        if (t < 4) {
            int k0 = t * 32;
#pragma unroll
            for (int i = 0; i < 2; ++i) {          // Ao tile 64x32 (row stride 128)
                int idx = tid + 256 * i;
                int rr = idx >> 3, c4 = idx & 7;
                float4 v = *(const float4*)(AoB + (size_t)rr * OBJ + k0 + c4 * 4);
                Asm[rr][c4 * 4 + 0] = v.x; Asm[rr][c4 * 4 + 1] = v.y;
                Asm[rr][c4 * 4 + 2] = v.z; Asm[rr][c4 * 4 + 3] = v.w;
            }
#pragma unroll
            for (int i = 0; i < 2; ++i) {          // xw tile 32x64
                int idx = tid + 256 * i;
                int rr = idx >> 4, c4 = idx & 15;
                *(float4*)(&Bs[rr][c4 * 4]) =
                    *(const float4*)(xwB + (size_t)(k0 + rr) * DD + n0 + c4 * 4);
            }
        } else {
#pragma unroll
            for (int i = 0; i < 2; ++i) {          // Ar tile 64x32 (row stride 32)
                int idx = tid + 256 * i;
                int rr = idx >> 3, c4 = idx & 7;
                float4 v = *(const float4*)(ArB + (size_t)rr * RR + c4 * 4);
                Asm[rr][c4 * 4 + 0] = v.x; Asm[rr][c4 * 4 + 1] = v.y;
                Asm[rr][c4 * 4 + 2] = v.z; Asm[rr][c4 * 4 + 3] = v.w;
            }
#pragma unroll
            for (int i = 0; i < 2; ++i) {          // relpart tile 32x64
                int idx = tid + 256 * i;
                int rr = idx >> 4, c4 = idx & 15;
                *(float4*)(&Bs[rr][c4 * 4]) =
                    *(const float4*)(rp + (size_t)rr * DD + n0 + c4 * 4);
            }
        }
        __syncthreads();
#pragma unroll
        for (int kk = 0; kk < 32; ++kk) {
            float a0 = Asm[ty * 4 + 0][kk];
            float a1 = Asm[ty * 4 + 1][kk];
            float a2 = Asm[ty * 4 + 2][kk];
            float a3 = Asm[ty * 4 + 3][kk];
            float4 bv = *(const float4*)(&Bs[kk][tx * 4]);
            acc[0][0] = fmaf(a0, bv.x, acc[0][0]);
            acc[0][1] = fmaf(a0, bv.y, acc[0][1]);
            acc[0][2] = fmaf(a0, bv.z, acc[0][2]);
            acc[0][3] = fmaf(a0, bv.w, acc[0][3]);
            acc[1][0] = fmaf(a1, bv.x, acc[1][0]);
            acc[1][1] = fmaf(a1, bv.y, acc[1][1]);
            acc[1][2] = fmaf(a1, bv.z, acc[1][2]);
            acc[1][3] = fmaf(a1, bv.w, acc[1][3]);
            acc[2][0] = fmaf(a2, bv.x, acc[2][0]);
            acc[2][1] = fmaf(a2, bv.y, acc[2][1]);
            acc[2][2] = fmaf(a2, bv.z, acc[2][2]);
            acc[2][3] = fmaf(a2, bv.w, acc[2][3]);
            acc[3][0] = fmaf(a3, bv.x, acc[3][0]);
            acc[3][1] = fmaf(a3, bv.y, acc[3][1]);
            acc[3][2] = fmaf(a3, bv.z, acc[3][2]);
            acc[3][3] = fmaf(a3, bv.w, acc[3][3]);
        }
        __syncthreads();
    }

    float4 b2v = *(const float4*)(b2 + (size_t)d * DD + n0 + tx * 4);
#pragma unroll
    for (int i = 0; i < 4; ++i) {
        int m = m0 + ty * 4 + i;
        float asv = As[(size_t)b * OBJ + m];
        size_t base = ((size_t)b * OBJ + m) * DD + n0 + tx * 4;
        float4 hv = *(const float4*)(h1 + base);
        float4 xv = *(const float4*)(xin + base);
        float4 o;
        o.x = tanhf(acc[i][0] + asv * b2v.x + hv.x + xv.x);
        o.y = tanhf(acc[i][1] + asv * b2v.y + hv.y + xv.y);
        o.z = tanhf(acc[i][2] + asv * b2v.z + hv.z + xv.z);
        o.w = tanhf(acc[i][3] + asv * b2v.w + hv.w + xv.w);
        *(float4*)(xout + base) = o;
    }
}

// ---------------------------------------------------------------------------
extern "C" void kernel_launch(void* const* d_in, const int* in_sizes, int n_in,
                              void* d_out, int out_size, void* d_ws, size_t ws_size,
                              hipStream_t stream) {
    const float* x    = (const float*)d_in[0];   // [32,128,256]
    const float* A    = (const float*)d_in[1];   // [32,128,4096]
    const float* rel  = (const float*)d_in[2];   // [32,64]
    const float* W1   = (const float*)d_in[3];   // [3,256,256]
    const float* b1   = (const float*)d_in[4];   // [3,256]
    const float* W2   = (const float*)d_in[5];   // [3,320,256]
    const float* b2   = (const float*)d_in[6];   // [3,256]
    float* out = (float*)d_out;

    float* Ao      = (float*)d_ws;                       // 32*128*128
    float* Ar      = Ao + (size_t)BS * OBJ * OBJ;        // 32*128*32
    float* As_     = Ar + (size_t)BS * OBJ * RR;         // 32*128
    float* relpart = As_ + (size_t)BS * OBJ;             // 3*32*256
    float* xwbuf   = relpart + (size_t)NDEPTH * RR * DD; // 32*128*256
    float* h1buf   = xwbuf + (size_t)BS * OBJ * DD;      // 32*128*256
    float* xbuf    = h1buf + (size_t)BS * OBJ * DD;      // 32*128*256

    k_reduceA<<<dim3(BS * OBJ / 4), dim3(256), 0, stream>>>(A, Ao, Ar, As_);
    k_rel<<<dim3(NDEPTH * RR), dim3(256), 0, stream>>>(rel, W2, relpart);

    const float* xcur = x;
    for (int d = 0; d < NDEPTH; ++d) {
        float* xnext = (d == NDEPTH - 1) ? out : xbuf;
        k_gemm1<<<dim3(8, 64), dim3(256), 0, stream>>>(xcur, W1, W2, b1, d, h1buf, xwbuf);
        k_agg<<<dim3(4, 2, BS), dim3(256), 0, stream>>>(Ao, Ar, As_, relpart, b2, d,
                                                        xwbuf, h1buf, xcur, xnext);
        xcur = xnext;
    }
}